// Round 1
// baseline (186.595 us; speedup 1.0000x reference)
//
#include <hip/hip_runtime.h>

// GNN layer: deg-normalized aggregation (CSR-by-dest gather) -> Linear+ReLU -> LayerNorm
// N=10000, E=640000, D=128 (D hard-assumed 128; N,E derived from in_sizes)

#define DFEAT 128

__global__ void zero_ints_kernel(int* __restrict__ p, int n) {
    int i = blockIdx.x * blockDim.x + threadIdx.x;
    if (i < n) p[i] = 0;
}

// edge_index: [0..E) = row (sources), [E..2E) = col (dests)
__global__ void count_kernel(const int* __restrict__ ei, int E,
                             int* __restrict__ cnt_row, int* __restrict__ cnt_in) {
    int i = blockIdx.x * blockDim.x + threadIdx.x;
    int stride = gridDim.x * blockDim.x;
    for (int e = i; e < E; e += stride) {
        atomicAdd(&cnt_row[ei[e]], 1);
        atomicAdd(&cnt_in[ei[E + e]], 1);
    }
}

__global__ void dinv_kernel(const int* __restrict__ cnt_row, float* __restrict__ dinv, int N) {
    int i = blockIdx.x * blockDim.x + threadIdx.x;
    // deg = out-count + 1 (self-loop); always >= 1
    if (i < N) dinv[i] = 1.0f / (float)(cnt_row[i] + 1);
}

// single-block exclusive scan over cnt_in -> offs[0..N], and cursor = offs copy
__global__ void scan_kernel(const int* __restrict__ cnt, int* __restrict__ offs,
                            int* __restrict__ cursor, int N) {
    __shared__ int buf[1024];
    __shared__ int carryS;
    int t = threadIdx.x;
    if (t == 0) carryS = 0;
    __syncthreads();
    for (int base = 0; base < N; base += 1024) {
        int x = (base + t < N) ? cnt[base + t] : 0;
        buf[t] = x;
        __syncthreads();
        for (int off = 1; off < 1024; off <<= 1) {
            int v = (t >= off) ? buf[t - off] : 0;
            __syncthreads();
            buf[t] += v;
            __syncthreads();
        }
        int incl = buf[t];
        int carry = carryS;
        if (base + t < N) {
            int ex = carry + incl - x;
            offs[base + t] = ex;
            cursor[base + t] = ex;
        }
        __syncthreads();
        if (t == 1023) carryS = carry + incl;
        __syncthreads();
    }
    if (t == 0) offs[N] = carryS;
}

__global__ void fill_kernel(const int* __restrict__ ei, int E,
                            int* __restrict__ cursor, int* __restrict__ edge_src) {
    int i = blockIdx.x * blockDim.x + threadIdx.x;
    int stride = gridDim.x * blockDim.x;
    for (int e = i; e < E; e += stride) {
        int c = ei[E + e];
        int pos = atomicAdd(&cursor[c], 1);
        edge_src[pos] = ei[e];
    }
}

// One wave per destination node; lane holds float2 (feats 2t, 2t+1).
__global__ __launch_bounds__(64) void agg_kernel(
    const float* __restrict__ H, const float* __restrict__ dinv,
    const int* __restrict__ offs, const int* __restrict__ edge_src,
    float* __restrict__ Hagg, int N) {
    int c = blockIdx.x;
    if (c >= N) return;
    int t = threadIdx.x;  // 0..63
    const float2* __restrict__ H2 = (const float2*)H;
    float wc = dinv[c];
    float2 h = H2[c * 64 + t];
    float ax = h.x * wc, ay = h.y * wc;  // self-loop message
    int e = offs[c], end = offs[c + 1];
    for (; e + 4 <= end; e += 4) {
        int s0 = edge_src[e], s1 = edge_src[e + 1], s2 = edge_src[e + 2], s3 = edge_src[e + 3];
        float w0 = dinv[s0], w1 = dinv[s1], w2 = dinv[s2], w3 = dinv[s3];
        float2 h0 = H2[s0 * 64 + t];
        float2 h1 = H2[s1 * 64 + t];
        float2 h2 = H2[s2 * 64 + t];
        float2 h3 = H2[s3 * 64 + t];
        ax += h0.x * w0 + h1.x * w1 + h2.x * w2 + h3.x * w3;
        ay += h0.y * w0 + h1.y * w1 + h2.y * w2 + h3.y * w3;
    }
    for (; e < end; ++e) {
        int s = edge_src[e];
        float w = dinv[s];
        float2 hh = H2[s * 64 + t];
        ax += hh.x * w;
        ay += hh.y * w;
    }
    float2 out;
    out.x = ax;
    out.y = ay;
    ((float2*)Hagg)[c * 64 + t] = out;
}

// Fused: out = LN(relu(Hagg @ W^T + b)) * gamma + beta.
// HO is both input (Hagg) and output; each wave owns complete node rows.
// W staged in LDS transposed + XOR-swizzled: Wt[k*128 + (d ^ (k&31))] = W[d][k].
__global__ __launch_bounds__(256) void mmln_kernel(
    const float* __restrict__ W, const float* __restrict__ bias,
    const float* __restrict__ gamma, const float* __restrict__ beta,
    float* __restrict__ HO, int N) {
    __shared__ float Wt[128 * 128];
    int t = threadIdx.x;
    for (int i = t; i < 128 * 128; i += 256) {
        int d = i >> 7, k = i & 127;
        Wt[k * 128 + (d ^ (k & 31))] = W[i];
    }
    __syncthreads();

    int wave = t >> 6, lane = t & 63;
    int d0 = lane, d1 = lane + 64;
    float b0 = bias[d0], b1 = bias[d1];
    float g0 = gamma[d0], g1 = gamma[d1];
    float be0 = beta[d0], be1 = beta[d1];

    const int NB = 8;  // nodes per block pass, 2 per wave
    int nbatches = (N + NB - 1) / NB;
    for (int batch = blockIdx.x; batch < nbatches; batch += gridDim.x) {
        int node0 = batch * NB + wave * 2;
        int node1 = node0 + 1;
        bool has0 = node0 < N, has1 = node1 < N;
        const float* __restrict__ r0 = HO + (size_t)(has0 ? node0 : 0) * 128;
        const float* __restrict__ r1 = HO + (size_t)(has1 ? node1 : 0) * 128;
        float a00 = b0, a01 = b1;  // node0, feats d0/d1
        float a10 = b0, a11 = b1;  // node1
#pragma unroll 4
        for (int k = 0; k < 128; ++k) {
            float w0 = Wt[k * 128 + (d0 ^ (k & 31))];
            float w1 = Wt[k * 128 + (d1 ^ (k & 31))];
            float x0 = r0[k];
            float x1 = r1[k];
            a00 += x0 * w0;
            a01 += x0 * w1;
            a10 += x1 * w0;
            a11 += x1 * w1;
        }
        // node0 LN
        {
            float v0 = fmaxf(a00, 0.f), v1 = fmaxf(a01, 0.f);
            float s = v0 + v1, q = v0 * v0 + v1 * v1;
            for (int o = 32; o; o >>= 1) {
                s += __shfl_xor(s, o);
                q += __shfl_xor(q, o);
            }
            float mean = s * (1.0f / 128.0f);
            float var = q * (1.0f / 128.0f) - mean * mean;
            float rstd = rsqrtf(var + 1e-5f);
            if (has0) {
                HO[(size_t)node0 * 128 + d0] = (v0 - mean) * rstd * g0 + be0;
                HO[(size_t)node0 * 128 + d1] = (v1 - mean) * rstd * g1 + be1;
            }
        }
        // node1 LN
        {
            float v0 = fmaxf(a10, 0.f), v1 = fmaxf(a11, 0.f);
            float s = v0 + v1, q = v0 * v0 + v1 * v1;
            for (int o = 32; o; o >>= 1) {
                s += __shfl_xor(s, o);
                q += __shfl_xor(q, o);
            }
            float mean = s * (1.0f / 128.0f);
            float var = q * (1.0f / 128.0f) - mean * mean;
            float rstd = rsqrtf(var + 1e-5f);
            if (has1) {
                HO[(size_t)node1 * 128 + d0] = (v0 - mean) * rstd * g0 + be0;
                HO[(size_t)node1 * 128 + d1] = (v1 - mean) * rstd * g1 + be1;
            }
        }
        __syncthreads();
    }
}

extern "C" void kernel_launch(void* const* d_in, const int* in_sizes, int n_in,
                              void* d_out, int out_size, void* d_ws, size_t ws_size,
                              hipStream_t stream) {
    const float* H = (const float*)d_in[0];
    const int* ei = (const int*)d_in[1];
    const float* W = (const float*)d_in[3];
    const float* bias = (const float*)d_in[4];
    const float* gamma = (const float*)d_in[5];
    const float* beta = (const float*)d_in[6];
    float* out = (float*)d_out;

    const int N = in_sizes[0] / DFEAT;
    const int E = in_sizes[1] / 2;

    // workspace layout (256B-aligned chunks)
    char* w = (char*)d_ws;
    auto alloc = [&](size_t bytes) {
        char* p = w;
        w += (bytes + 255) & ~(size_t)255;
        return p;
    };
    int* cnt_row = (int*)alloc((size_t)N * 4);
    int* cnt_in = (int*)alloc((size_t)N * 4);
    int* offs = (int*)alloc((size_t)(N + 1) * 4);
    int* cursor = (int*)alloc((size_t)N * 4);
    float* dinv = (float*)alloc((size_t)N * 4);
    int* edge_src = (int*)alloc((size_t)E * 4);
    (void)ws_size;

    // 1. zero counters (cnt_row, cnt_in are adjacent allocations but zero separately for safety)
    {
        int n2 = N;
        int blocks = (n2 + 255) / 256;
        zero_ints_kernel<<<blocks, 256, 0, stream>>>(cnt_row, n2);
        zero_ints_kernel<<<blocks, 256, 0, stream>>>(cnt_in, n2);
    }
    // 2. count out-degree (row) and in-degree (col)
    count_kernel<<<1024, 256, 0, stream>>>(ei, E, cnt_row, cnt_in);
    // 3. dinv = 1/(outdeg+1)
    dinv_kernel<<<(N + 255) / 256, 256, 0, stream>>>(cnt_row, dinv, N);
    // 4. exclusive scan of in-degree -> offs, cursor
    scan_kernel<<<1, 1024, 0, stream>>>(cnt_in, offs, cursor, N);
    // 5. fill CSR edge_src
    fill_kernel<<<1024, 256, 0, stream>>>(ei, E, cursor, edge_src);
    // 6. aggregate into d_out (used as Hagg scratch)
    agg_kernel<<<N, 64, 0, stream>>>(H, dinv, offs, edge_src, out, N);
    // 7. fused matmul + bias + relu + layernorm, in-place on d_out
    {
        int nbatches = (N + 7) / 8;
        int grid = nbatches < 512 ? nbatches : 512;
        mmln_kernel<<<grid, 256, 0, stream>>>(W, bias, gamma, beta, out, N);
    }
}

// Round 2
// 126.695 us; speedup vs baseline: 1.4728x; 1.4728x over previous
//
#include <hip/hip_runtime.h>

// GNN layer: deg-normalized aggregation -> Linear+ReLU -> LayerNorm
// N=10000, E=640000, D=128. CSR-by-dest built with ZERO global atomics:
// LDS-privatized per-block histograms + cross-block scan.

#define DFEAT 128
#define NBLK 32      // histogram partitions (one CU each)
#define MAXN 10240   // compile-time bin capacity (N=10000)

// Packed per-block histogram: low16 = out-degree(row), high16 = in-degree(col).
// Max per-block count <= Epb=20000 < 32768, so halves never interfere.
__global__ __launch_bounds__(1024) void hist_kernel(
    const int* __restrict__ ei, int E, int Epb, int N,
    int* __restrict__ histR, int* __restrict__ histC) {
    __shared__ unsigned int h[MAXN];
    int t = threadIdx.x;
    int b = blockIdx.x;
    for (int i = t; i < N; i += 1024) h[i] = 0u;
    __syncthreads();
    int e0 = b * Epb, e1 = min(E, e0 + Epb);
    for (int e = e0 + t; e < e1; e += 1024) {
        atomicAdd(&h[ei[e]], 1u);            // row / source -> low16
        atomicAdd(&h[ei[E + e]], 0x10000u);  // col / dest   -> high16
    }
    __syncthreads();
    for (int i = t; i < N; i += 1024) {
        unsigned int v = h[i];
        histR[b * N + i] = (int)(v & 0xffffu);
        histC[b * N + i] = (int)(v >> 16);
    }
}

// Per-bin: sum histR across blocks -> dinv; exclusive-prefix histC across
// blocks (in place -> blkpref) and total -> tot.
__global__ void colscan_kernel(int* __restrict__ histC, const int* __restrict__ histR,
                               float* __restrict__ dinv, int* __restrict__ tot, int N) {
    int b = blockIdx.x * blockDim.x + threadIdx.x;
    if (b >= N) return;
    int vR[NBLK], vC[NBLK];
#pragma unroll
    for (int k = 0; k < NBLK; ++k) {
        vR[k] = histR[k * N + b];
        vC[k] = histC[k * N + b];
    }
    int sR = 0, sC = 0;
#pragma unroll
    for (int k = 0; k < NBLK; ++k) {
        sR += vR[k];
        histC[k * N + b] = sC;
        sC += vC[k];
    }
    dinv[b] = 1.0f / (float)(sR + 1);  // +1 self-loop; always >= 1
    tot[b] = sC;
}

// Single-block exclusive scan (shfl-based) over tot -> offs[0..N]
__global__ __launch_bounds__(1024) void scan_kernel(const int* __restrict__ cnt,
                                                    int* __restrict__ offs, int N) {
    __shared__ int wsum[16];
    __shared__ int carryS;
    int t = threadIdx.x;
    int lane = t & 63, wv = t >> 6;
    if (t == 0) carryS = 0;
    __syncthreads();
    for (int base = 0; base < N; base += 1024) {
        int x = (base + t < N) ? cnt[base + t] : 0;
        int inc = x;
        for (int o = 1; o < 64; o <<= 1) {
            int v = __shfl_up(inc, o);
            if (lane >= o) inc += v;
        }
        if (lane == 63) wsum[wv] = inc;
        __syncthreads();
        if (wv == 0) {
            int s = (lane < 16) ? wsum[lane] : 0;
            for (int o = 1; o < 16; o <<= 1) {
                int v = __shfl_up(s, o);
                if (lane >= o) s += v;
            }
            if (lane < 16) wsum[lane] = s;
        }
        __syncthreads();
        int wpre = (wv == 0) ? 0 : wsum[wv - 1];
        int carry = carryS;
        if (base + t < N) offs[base + t] = carry + wpre + inc - x;
        __syncthreads();
        if (t == 1023) carryS = carry + wpre + inc;
        __syncthreads();
    }
    if (t == 0) offs[N] = carryS;
}

// Fill CSR: local ranks re-derived via LDS atomics (any distinct assignment
// within a (block,bin) slice is valid). No global atomics.
__global__ __launch_bounds__(1024) void fill_kernel(
    const int* __restrict__ ei, int E, int Epb, int N,
    const int* __restrict__ offs, const int* __restrict__ blkpref,
    unsigned short* __restrict__ edge_src) {
    __shared__ int hC[MAXN];
    int t = threadIdx.x;
    int b = blockIdx.x;
    for (int i = t; i < N; i += 1024) hC[i] = 0;
    __syncthreads();
    const int* __restrict__ pre = blkpref + b * N;
    int e0 = b * Epb, e1 = min(E, e0 + Epb);
    for (int e = e0 + t; e < e1; e += 1024) {
        int c = ei[E + e];
        int r = atomicAdd(&hC[c], 1);
        edge_src[offs[c] + pre[c] + r] = (unsigned short)ei[e];
    }
}

// One wave per destination node; lane holds float2 (feats 2t, 2t+1).
__global__ __launch_bounds__(64) void agg_kernel(
    const float* __restrict__ H, const float* __restrict__ dinv,
    const int* __restrict__ offs, const unsigned short* __restrict__ edge_src,
    float* __restrict__ Hagg, int N) {
    int c = blockIdx.x;
    if (c >= N) return;
    int t = threadIdx.x;  // 0..63
    const float2* __restrict__ H2 = (const float2*)H;
    float wc = dinv[c];
    float2 h = H2[c * 64 + t];
    float ax = h.x * wc, ay = h.y * wc;  // self-loop message
    int e = offs[c], end = offs[c + 1];
    for (; e + 4 <= end; e += 4) {
        int s0 = edge_src[e], s1 = edge_src[e + 1], s2 = edge_src[e + 2], s3 = edge_src[e + 3];
        float w0 = dinv[s0], w1 = dinv[s1], w2 = dinv[s2], w3 = dinv[s3];
        float2 h0 = H2[s0 * 64 + t];
        float2 h1 = H2[s1 * 64 + t];
        float2 h2 = H2[s2 * 64 + t];
        float2 h3 = H2[s3 * 64 + t];
        ax += h0.x * w0 + h1.x * w1 + h2.x * w2 + h3.x * w3;
        ay += h0.y * w0 + h1.y * w1 + h2.y * w2 + h3.y * w3;
    }
    for (; e < end; ++e) {
        int s = edge_src[e];
        float w = dinv[s];
        float2 hh = H2[s * 64 + t];
        ax += hh.x * w;
        ay += hh.y * w;
    }
    float2 out;
    out.x = ax;
    out.y = ay;
    ((float2*)Hagg)[c * 64 + t] = out;
}

// Fused: out = LN(relu(Hagg @ W^T + b)) * gamma + beta (in place on HO).
// W staged in LDS transposed + XOR-swizzled.
__global__ __launch_bounds__(256) void mmln_kernel(
    const float* __restrict__ W, const float* __restrict__ bias,
    const float* __restrict__ gamma, const float* __restrict__ beta,
    float* __restrict__ HO, int N) {
    __shared__ float Wt[128 * 128];
    int t = threadIdx.x;
    for (int i = t; i < 128 * 128; i += 256) {
        int d = i >> 7, k = i & 127;
        Wt[k * 128 + (d ^ (k & 31))] = W[i];
    }
    __syncthreads();

    int wave = t >> 6, lane = t & 63;
    int d0 = lane, d1 = lane + 64;
    float b0 = bias[d0], b1 = bias[d1];
    float g0 = gamma[d0], g1 = gamma[d1];
    float be0 = beta[d0], be1 = beta[d1];

    const int NB = 8;  // nodes per block pass, 2 per wave
    int nbatches = (N + NB - 1) / NB;
    for (int batch = blockIdx.x; batch < nbatches; batch += gridDim.x) {
        int node0 = batch * NB + wave * 2;
        int node1 = node0 + 1;
        bool has0 = node0 < N, has1 = node1 < N;
        const float* __restrict__ r0 = HO + (size_t)(has0 ? node0 : 0) * 128;
        const float* __restrict__ r1 = HO + (size_t)(has1 ? node1 : 0) * 128;
        float a00 = b0, a01 = b1;
        float a10 = b0, a11 = b1;
#pragma unroll 4
        for (int k = 0; k < 128; ++k) {
            float w0 = Wt[k * 128 + (d0 ^ (k & 31))];
            float w1 = Wt[k * 128 + (d1 ^ (k & 31))];
            float x0 = r0[k];
            float x1 = r1[k];
            a00 += x0 * w0;
            a01 += x0 * w1;
            a10 += x1 * w0;
            a11 += x1 * w1;
        }
        {
            float v0 = fmaxf(a00, 0.f), v1 = fmaxf(a01, 0.f);
            float s = v0 + v1, q = v0 * v0 + v1 * v1;
            for (int o = 32; o; o >>= 1) {
                s += __shfl_xor(s, o);
                q += __shfl_xor(q, o);
            }
            float mean = s * (1.0f / 128.0f);
            float var = q * (1.0f / 128.0f) - mean * mean;
            float rstd = rsqrtf(var + 1e-5f);
            if (has0) {
                HO[(size_t)node0 * 128 + d0] = (v0 - mean) * rstd * g0 + be0;
                HO[(size_t)node0 * 128 + d1] = (v1 - mean) * rstd * g1 + be1;
            }
        }
        {
            float v0 = fmaxf(a10, 0.f), v1 = fmaxf(a11, 0.f);
            float s = v0 + v1, q = v0 * v0 + v1 * v1;
            for (int o = 32; o; o >>= 1) {
                s += __shfl_xor(s, o);
                q += __shfl_xor(q, o);
            }
            float mean = s * (1.0f / 128.0f);
            float var = q * (1.0f / 128.0f) - mean * mean;
            float rstd = rsqrtf(var + 1e-5f);
            if (has1) {
                HO[(size_t)node1 * 128 + d0] = (v0 - mean) * rstd * g0 + be0;
                HO[(size_t)node1 * 128 + d1] = (v1 - mean) * rstd * g1 + be1;
            }
        }
        __syncthreads();
    }
}

extern "C" void kernel_launch(void* const* d_in, const int* in_sizes, int n_in,
                              void* d_out, int out_size, void* d_ws, size_t ws_size,
                              hipStream_t stream) {
    const float* H = (const float*)d_in[0];
    const int* ei = (const int*)d_in[1];
    const float* W = (const float*)d_in[3];
    const float* bias = (const float*)d_in[4];
    const float* gamma = (const float*)d_in[5];
    const float* beta = (const float*)d_in[6];
    float* out = (float*)d_out;

    const int N = in_sizes[0] / DFEAT;  // 10000 (<= MAXN)
    const int E = in_sizes[1] / 2;      // 640000
    const int Epb = (E + NBLK - 1) / NBLK;

    // workspace layout (256B-aligned); histR overlays edge_src region
    // (histR dead after colscan, edge_src written in fill).
    char* w = (char*)d_ws;
    auto alloc = [&](size_t bytes) {
        char* p = w;
        w += (bytes + 255) & ~(size_t)255;
        return p;
    };
    size_t histBytes = (size_t)NBLK * N * 4;
    int* histC = (int*)alloc(histBytes);  // becomes blkpref in colscan
    size_t r1 = histBytes > (size_t)E * 2 ? histBytes : (size_t)E * 2;
    char* region1 = alloc(r1);
    int* histR = (int*)region1;
    unsigned short* edge_src = (unsigned short*)region1;
    int* offs = (int*)alloc((size_t)(N + 1) * 4);
    int* tot = (int*)alloc((size_t)N * 4);
    float* dinv = (float*)alloc((size_t)N * 4);
    (void)ws_size;

    hist_kernel<<<NBLK, 1024, 0, stream>>>(ei, E, Epb, N, histR, histC);
    colscan_kernel<<<(N + 255) / 256, 256, 0, stream>>>(histC, histR, dinv, tot, N);
    scan_kernel<<<1, 1024, 0, stream>>>(tot, offs, N);
    fill_kernel<<<NBLK, 1024, 0, stream>>>(ei, E, Epb, N, offs, histC, edge_src);
    agg_kernel<<<N, 64, 0, stream>>>(H, dinv, offs, edge_src, out, N);
    {
        int nbatches = (N + 7) / 8;
        int grid = nbatches < 512 ? nbatches : 512;
        mmln_kernel<<<grid, 256, 0, stream>>>(W, bias, gamma, beta, out, N);
    }
}

// Round 3
// 110.343 us; speedup vs baseline: 1.6911x; 1.1482x over previous
//
#include <hip/hip_runtime.h>

// GNN layer: deg-normalized aggregation -> Linear+ReLU -> LayerNorm
// N=10000, E=640000, D=128. CSR-by-dest with ZERO global atomics:
// per-block LDS histograms record per-edge ranks; fill is a stateless
// high-occupancy scatter using pos = offs[c] + blkpref[b][c] + rank[e].

#define DFEAT 128
#define MAXN 10240   // compile-time bin capacity (N=10000)

// Packed per-block histogram in LDS: low16 = out-degree(row), high16 = in-degree(col).
// Per-block edge count Epb <= 40000 (nblk>=16) so halves never carry.
// Also records each edge's within-(block,bin) rank for the dest histogram.
__global__ __launch_bounds__(1024) void hist_kernel(
    const int* __restrict__ ei, int E, int Epb, int N,
    int* __restrict__ packedHist, unsigned short* __restrict__ rank16) {
    __shared__ unsigned int h[MAXN];
    int t = threadIdx.x;
    int b = blockIdx.x;
    for (int i = t; i < N; i += 1024) h[i] = 0u;
    __syncthreads();
    int e0 = b * Epb, e1 = min(E, e0 + Epb);
    for (int e = e0 + t; e < e1; e += 1024) {
        atomicAdd(&h[ei[e]], 1u);  // row / source -> low16
        unsigned int old = atomicAdd(&h[ei[E + e]], 0x10000u);  // col/dest -> high16
        rank16[e] = (unsigned short)(old >> 16);
    }
    __syncthreads();
    for (int i = t; i < N; i += 1024) packedHist[b * N + i] = (int)h[i];
}

// Per-bin: sum row counts -> dinv; exclusive-prefix col counts across blocks
// IN PLACE (packedHist -> blkpref, 32-bit) and total -> tot.
// Access k*N+b is coalesced across adjacent threads.
__global__ void colscan_kernel(int* __restrict__ packedHist, float* __restrict__ dinv,
                               int* __restrict__ tot, int N, int nblk) {
    int b = blockIdx.x * blockDim.x + threadIdx.x;
    if (b >= N) return;
    int sR = 0, sC = 0;
    for (int k = 0; k < nblk; ++k) {
        unsigned int v = (unsigned int)packedHist[k * N + b];
        sR += (int)(v & 0xffffu);
        packedHist[k * N + b] = sC;
        sC += (int)(v >> 16);
    }
    dinv[b] = 1.0f / (float)(sR + 1);  // +1 self-loop; always >= 1
    tot[b] = sC;
}

// Single-block exclusive scan (shfl-based) over tot -> offs[0..N]
__global__ __launch_bounds__(1024) void scan_kernel(const int* __restrict__ cnt,
                                                    int* __restrict__ offs, int N) {
    __shared__ int wsum[16];
    __shared__ int carryS;
    int t = threadIdx.x;
    int lane = t & 63, wv = t >> 6;
    if (t == 0) carryS = 0;
    __syncthreads();
    for (int base = 0; base < N; base += 1024) {
        int x = (base + t < N) ? cnt[base + t] : 0;
        int inc = x;
        for (int o = 1; o < 64; o <<= 1) {
            int v = __shfl_up(inc, o);
            if (lane >= o) inc += v;
        }
        if (lane == 63) wsum[wv] = inc;
        __syncthreads();
        if (wv == 0) {
            int s = (lane < 16) ? wsum[lane] : 0;
            for (int o = 1; o < 16; o <<= 1) {
                int v = __shfl_up(s, o);
                if (lane >= o) s += v;
            }
            if (lane < 16) wsum[lane] = s;
        }
        __syncthreads();
        int wpre = (wv == 0) ? 0 : wsum[wv - 1];
        int carry = carryS;
        if (base + t < N) offs[base + t] = carry + wpre + inc - x;
        __syncthreads();
        if (t == 1023) carryS = carry + wpre + inc;
        __syncthreads();
    }
    if (t == 0) offs[N] = carryS;
}

// Stateless CSR fill: full-occupancy grid-stride, no LDS, no atomics.
__global__ __launch_bounds__(256) void fill_kernel(
    const int* __restrict__ ei, int E, int Epb, int N,
    const int* __restrict__ offs, const int* __restrict__ blkpref,
    const unsigned short* __restrict__ rank16, unsigned short* __restrict__ edge_src) {
    int i = blockIdx.x * blockDim.x + threadIdx.x;
    int stride = gridDim.x * blockDim.x;
    for (int e = i; e < E; e += stride) {
        int c = ei[E + e];
        int b = e / Epb;
        int pos = offs[c] + blkpref[b * N + c] + (int)rank16[e];
        edge_src[pos] = (unsigned short)ei[e];
    }
}

// One wave per destination node; lane holds float2 (feats 2t, 2t+1).
__global__ __launch_bounds__(64) void agg_kernel(
    const float* __restrict__ H, const float* __restrict__ dinv,
    const int* __restrict__ offs, const unsigned short* __restrict__ edge_src,
    float* __restrict__ Hagg, int N) {
    int c = blockIdx.x;
    if (c >= N) return;
    int t = threadIdx.x;  // 0..63
    const float2* __restrict__ H2 = (const float2*)H;
    float wc = dinv[c];
    float2 h = H2[c * 64 + t];
    float ax = h.x * wc, ay = h.y * wc;  // self-loop message
    int e = offs[c], end = offs[c + 1];
    for (; e + 4 <= end; e += 4) {
        int s0 = edge_src[e], s1 = edge_src[e + 1], s2 = edge_src[e + 2], s3 = edge_src[e + 3];
        float w0 = dinv[s0], w1 = dinv[s1], w2 = dinv[s2], w3 = dinv[s3];
        float2 h0 = H2[s0 * 64 + t];
        float2 h1 = H2[s1 * 64 + t];
        float2 h2 = H2[s2 * 64 + t];
        float2 h3 = H2[s3 * 64 + t];
        ax += h0.x * w0 + h1.x * w1 + h2.x * w2 + h3.x * w3;
        ay += h0.y * w0 + h1.y * w1 + h2.y * w2 + h3.y * w3;
    }
    for (; e < end; ++e) {
        int s = edge_src[e];
        float w = dinv[s];
        float2 hh = H2[s * 64 + t];
        ax += hh.x * w;
        ay += hh.y * w;
    }
    float2 out;
    out.x = ax;
    out.y = ay;
    ((float2*)Hagg)[c * 64 + t] = out;
}

// Fused: out = LN(relu(Hagg @ W^T + b)) * gamma + beta (in place on HO).
// W staged in LDS transposed + XOR-swizzled.
__global__ __launch_bounds__(256) void mmln_kernel(
    const float* __restrict__ W, const float* __restrict__ bias,
    const float* __restrict__ gamma, const float* __restrict__ beta,
    float* __restrict__ HO, int N) {
    __shared__ float Wt[128 * 128];
    int t = threadIdx.x;
    for (int i = t; i < 128 * 128; i += 256) {
        int d = i >> 7, k = i & 127;
        Wt[k * 128 + (d ^ (k & 31))] = W[i];
    }
    __syncthreads();

    int wave = t >> 6, lane = t & 63;
    int d0 = lane, d1 = lane + 64;
    float b0 = bias[d0], b1 = bias[d1];
    float g0 = gamma[d0], g1 = gamma[d1];
    float be0 = beta[d0], be1 = beta[d1];

    const int NB = 8;  // nodes per block pass, 2 per wave
    int nbatches = (N + NB - 1) / NB;
    for (int batch = blockIdx.x; batch < nbatches; batch += gridDim.x) {
        int node0 = batch * NB + wave * 2;
        int node1 = node0 + 1;
        bool has0 = node0 < N, has1 = node1 < N;
        const float* __restrict__ r0 = HO + (size_t)(has0 ? node0 : 0) * 128;
        const float* __restrict__ r1 = HO + (size_t)(has1 ? node1 : 0) * 128;
        float a00 = b0, a01 = b1;
        float a10 = b0, a11 = b1;
#pragma unroll 4
        for (int k = 0; k < 128; ++k) {
            float w0 = Wt[k * 128 + (d0 ^ (k & 31))];
            float w1 = Wt[k * 128 + (d1 ^ (k & 31))];
            float x0 = r0[k];
            float x1 = r1[k];
            a00 += x0 * w0;
            a01 += x0 * w1;
            a10 += x1 * w0;
            a11 += x1 * w1;
        }
        {
            float v0 = fmaxf(a00, 0.f), v1 = fmaxf(a01, 0.f);
            float s = v0 + v1, q = v0 * v0 + v1 * v1;
            for (int o = 32; o; o >>= 1) {
                s += __shfl_xor(s, o);
                q += __shfl_xor(q, o);
            }
            float mean = s * (1.0f / 128.0f);
            float var = q * (1.0f / 128.0f) - mean * mean;
            float rstd = rsqrtf(var + 1e-5f);
            if (has0) {
                HO[(size_t)node0 * 128 + d0] = (v0 - mean) * rstd * g0 + be0;
                HO[(size_t)node0 * 128 + d1] = (v1 - mean) * rstd * g1 + be1;
            }
        }
        {
            float v0 = fmaxf(a10, 0.f), v1 = fmaxf(a11, 0.f);
            float s = v0 + v1, q = v0 * v0 + v1 * v1;
            for (int o = 32; o; o >>= 1) {
                s += __shfl_xor(s, o);
                q += __shfl_xor(q, o);
            }
            float mean = s * (1.0f / 128.0f);
            float var = q * (1.0f / 128.0f) - mean * mean;
            float rstd = rsqrtf(var + 1e-5f);
            if (has1) {
                HO[(size_t)node1 * 128 + d0] = (v0 - mean) * rstd * g0 + be0;
                HO[(size_t)node1 * 128 + d1] = (v1 - mean) * rstd * g1 + be1;
            }
        }
    }
}

extern "C" void kernel_launch(void* const* d_in, const int* in_sizes, int n_in,
                              void* d_out, int out_size, void* d_ws, size_t ws_size,
                              hipStream_t stream) {
    const float* H = (const float*)d_in[0];
    const int* ei = (const int*)d_in[1];
    const float* W = (const float*)d_in[3];
    const float* bias = (const float*)d_in[4];
    const float* gamma = (const float*)d_in[5];
    const float* beta = (const float*)d_in[6];
    float* out = (float*)d_out;

    const int N = in_sizes[0] / DFEAT;  // 10000 (<= MAXN)
    const int E = in_sizes[1] / 2;      // 640000

    auto align256 = [](size_t x) { return (x + 255) & ~(size_t)255; };
    // pick largest nblk in {64,32,16} whose workspace fits
    int nblk = 64;
    while (nblk > 16) {
        size_t need = align256((size_t)nblk * N * 4) + align256((size_t)E * 2) * 2 +
                      align256((size_t)(N + 1) * 4) + align256((size_t)N * 4) * 2;
        if (need <= ws_size || ws_size == 0) break;
        nblk >>= 1;
    }
    const int Epb = (E + nblk - 1) / nblk;  // <= 40000 -> ranks fit u16

    char* w = (char*)d_ws;
    auto alloc = [&](size_t bytes) {
        char* p = w;
        w += (bytes + 255) & ~(size_t)255;
        return p;
    };
    int* packedHist = (int*)alloc((size_t)nblk * N * 4);  // -> blkpref after colscan
    unsigned short* rank16 = (unsigned short*)alloc((size_t)E * 2);
    unsigned short* edge_src = (unsigned short*)alloc((size_t)E * 2);
    int* offs = (int*)alloc((size_t)(N + 1) * 4);
    int* tot = (int*)alloc((size_t)N * 4);
    float* dinv = (float*)alloc((size_t)N * 4);

    hist_kernel<<<nblk, 1024, 0, stream>>>(ei, E, Epb, N, packedHist, rank16);
    colscan_kernel<<<(N + 255) / 256, 256, 0, stream>>>(packedHist, dinv, tot, N, nblk);
    scan_kernel<<<1, 1024, 0, stream>>>(tot, offs, N);
    {
        int grid = (E + 255) / 256;
        if (grid > 2048) grid = 2048;
        fill_kernel<<<grid, 256, 0, stream>>>(ei, E, Epb, N, offs, packedHist, rank16, edge_src);
    }
    agg_kernel<<<N, 64, 0, stream>>>(H, dinv, offs, edge_src, out, N);
    {
        int nbatches = (N + 7) / 8;
        int grid = nbatches < 512 ? nbatches : 512;
        mmln_kernel<<<grid, 256, 0, stream>>>(W, bias, gamma, beta, out, N);
    }
}